// Round 7
// baseline (318.629 us; speedup 1.0000x reference)
//
#include <hip/hip_runtime.h>
#include <hip/hip_cooperative_groups.h>
#include <math.h>

namespace cg = cooperative_groups;

#define N_ATOMS 512
#define N_MOL   16
#define HIDDEN  128
#define FILTERS 128
#define NUM_RBF 50
#define CUTOFF  10.0f
#define N_LAYERS 3

#define KBINS  1024              // lerp bins over [0, CUTOFF]
#define NBINS  (KBINS + 2)       // bins evaluated 0..1025 (>=1024 give env=0)
#define PROWS  (KBINS + 1)       // pair rows 0..1024; row k = {phi_k, phi_{k+1}} bf16
#define TOTW   (N_LAYERS * NBINS)        // 3078 table wave-units
#define GRID   512
#define BLK    256
#define PI_F   3.14159265358979f

__device__ __forceinline__ unsigned short f2bf(float v) {
    unsigned u = __float_as_uint(v);
    u += 0x7fffu + ((u >> 16) & 1u);     // round-to-nearest-even
    return (unsigned short)(u >> 16);
}
__device__ __forceinline__ float bf2f(unsigned short u) {
    return __uint_as_float((unsigned)u << 16);
}

// ================= ONE cooperative kernel: front -> 3 layers -> pool =================
__global__ void __launch_bounds__(BLK, 2) k_all(
        const int* __restrict__ an, const float* __restrict__ pos,
        const int* __restrict__ batch, const float* __restrict__ emb,
        const float* __restrict__ fw1, const float* __restrict__ fb1,
        const float* __restrict__ fw2, const float* __restrict__ fb2,
        const float* __restrict__ d1w, const float* __restrict__ d1b,
        const float* __restrict__ d2w, const float* __restrict__ d2b,
        const float* __restrict__ ow1, const float* __restrict__ ob1,
        const float* __restrict__ ow2, const float* __restrict__ ob2,
        float* __restrict__ x, unsigned short* __restrict__ xjA,
        unsigned short* __restrict__ xjB, unsigned short* __restrict__ tab,
        float* __restrict__ out) {
    __shared__ float  s_pos[N_ATOMS * 3];        // persists across all phases (6 KB)
    __shared__ float2 s_kw[N_ATOMS];             // per-j distance cache (4 KB)
    __shared__ float  s_sh[4][HIDDEN];           // table h rows / misc (2 KB)
    __shared__ float  s_row[HIDDEN];             // emb row
    __shared__ float  s_red[2][FILTERS];
    __shared__ float  s_agg[FILTERS];
    __shared__ float  s_xn[HIDDEN];
    __shared__ float  s_mol[HIDDEN];
    __shared__ float  s_hh[64];
    __shared__ int    s_lo, s_cnt;

    cg::grid_group grid = cg::this_grid();
    int bid = blockIdx.x, t = threadIdx.x;

    // ---------------- stage pos once (persists in LDS for all layers) ----------------
    for (int idx = t; idx < N_ATOMS * 3; idx += BLK) s_pos[idx] = pos[idx];

    // ---------------- FRONT: emb + xj0 (1 atom = this block) ----------------
    {
        int i = bid;                              // GRID == N_ATOMS
        if (t < HIDDEN) s_row[t] = emb[(size_t)an[i] * HIDDEN + t];
        __syncthreads();
        int c = t & 127, sub = t >> 7;
        float a = 0.f;
        #pragma unroll 8
        for (int h = sub * 64; h < sub * 64 + 64; h++)
            a = fmaf(s_row[h], d1w[(size_t)h * FILTERS + c], a);
        s_red[sub][c] = a;
        __syncthreads();
        if (sub == 0) {
            xjA[(size_t)i * FILTERS + c] = f2bf(d1b[c] + s_red[0][c] + s_red[1][c]);
            x[(size_t)i * HIDDEN + c] = s_row[c];
        }
    }

    // ---------------- FRONT: filter tables (1 bin per wave, 2 uniform rounds) --------
    {
        int wv = t >> 6, lane = t & 63;
        #pragma unroll
        for (int r = 0; r < 2; r++) {
            int u  = bid * 4 + wv + r * (GRID * 4);
            int wc = u < TOTW ? u : TOTW - 1;     // clamp: uniform control flow
            int l  = wc / NBINS;
            int bin = wc - l * NBINS;
            float dd = bin * (CUTOFF / (float)KBINS);
            const float* w1g = fw1 + (size_t)l * NUM_RBF * FILTERS;
            const float* w2g = fw2 + (size_t)l * FILTERS * FILTERS;
            int c0 = lane, c1 = lane + 64;
            float h0 = fb1[l * FILTERS + c0];
            float h1 = fb1[l * FILTERS + c1];
            #pragma unroll 5
            for (int rr = 0; rr < NUM_RBF; rr++) {
                float cr = rr * (CUTOFF / (float)(NUM_RBF - 1));
                float xx = dd - cr;
                float rb = __expf(-xx * xx * 12.5f);      // 1/(2*w^2), w = 0.2
                h0 = fmaf(rb, w1g[rr * FILTERS + c0], h0);
                h1 = fmaf(rb, w1g[rr * FILTERS + c1], h1);
            }
            __syncthreads();
            s_sh[wv][c0] = h0 / (1.f + __expf(-h0));      // silu
            s_sh[wv][c1] = h1 / (1.f + __expf(-h1));
            __syncthreads();
            float o0 = fb2[l * FILTERS + c0];
            float o1 = fb2[l * FILTERS + c1];
            #pragma unroll 4
            for (int hh = 0; hh < FILTERS; hh++) {
                float hv = s_sh[wv][hh];                  // LDS broadcast
                o0 = fmaf(hv, w2g[hh * FILTERS + c0], o0);
                o1 = fmaf(hv, w2g[hh * FILTERS + c1], o1);
            }
            float env = (bin >= KBINS) ? 0.f
                      : 0.5f * (__cosf(dd * (PI_F / CUTOFF)) + 1.f);
            unsigned short p0 = f2bf(o0 * env), p1 = f2bf(o1 * env);
            size_t base = (size_t)l * PROWS * FILTERS * 2;
            if (u < TOTW) {
                if (bin <= KBINS) {                       // x-entry of row bin
                    tab[base + ((size_t)bin * FILTERS + c0) * 2 + 0] = p0;
                    tab[base + ((size_t)bin * FILTERS + c1) * 2 + 0] = p1;
                }
                if (bin >= 1) {                           // y-entry of row bin-1
                    tab[base + ((size_t)(bin - 1) * FILTERS + c0) * 2 + 1] = p0;
                    tab[base + ((size_t)(bin - 1) * FILTERS + c1) * 2 + 1] = p1;
                }
            }
        }
    }

    grid.sync();

    // ---------------- 3 LAYERS: j = bid; kw from persistent s_pos ----------------
    int j = bid;
    {   // distances for row j (once; reused all layers)
        float pjx = s_pos[j*3+0], pjy = s_pos[j*3+1], pjz = s_pos[j*3+2];
        for (int ii = t; ii < N_ATOMS; ii += BLK) {
            float dx = s_pos[ii*3+0] - pjx;
            float dy = s_pos[ii*3+1] - pjy;
            float dz = s_pos[ii*3+2] - pjz;
            float d  = sqrtf(dx*dx + dy*dy + dz*dz);
            int k; float w;
            if (ii == j || d >= CUTOFF) { k = KBINS; w = 0.f; }
            else {
                float tt = d * ((float)KBINS / CUTOFF);
                k = (int)tt;
                if (k > KBINS - 1) k = KBINS - 1;
                w = tt - (float)k;
            }
            s_kw[ii] = make_float2(w, __int_as_float(k));
        }
    }

    int f = t & 127, half = t >> 7;
    for (int l = 0; l < N_LAYERS; l++) {
        const unsigned int*   tabl = (const unsigned int*)(tab + (size_t)l * PROWS * FILTERS * 2);
        const unsigned short* xin  = (l & 1) ? xjB : xjA;
        unsigned short*       xout = (l & 1) ? xjA : xjB;
        const float* w2  = d2w + (size_t)l * FILTERS * HIDDEN;
        const float* b2  = d2b + (size_t)l * HIDDEN;
        const float* w1n = d1w + (size_t)(l + 1) * HIDDEN * FILTERS;   // unused when l==2
        const float* b1n = d1b + (size_t)(l + 1) * FILTERS;
        __syncthreads();
        // ---- aggregation: half sums 256 source atoms, 4 accumulators ----
        float acc0 = 0.f, acc1 = 0.f, acc2 = 0.f, acc3 = 0.f;
        int i0 = half * 256;
        #pragma unroll 2
        for (int ii = 0; ii < 256; ii += 4) {
            float2 kv0 = s_kw[i0 + ii];
            float2 kv1 = s_kw[i0 + ii + 1];
            float2 kv2 = s_kw[i0 + ii + 2];
            float2 kv3 = s_kw[i0 + ii + 3];
            unsigned int p0 = tabl[(size_t)__float_as_int(kv0.y) * FILTERS + f];
            unsigned int p1 = tabl[(size_t)__float_as_int(kv1.y) * FILTERS + f];
            unsigned int p2 = tabl[(size_t)__float_as_int(kv2.y) * FILTERS + f];
            unsigned int p3 = tabl[(size_t)__float_as_int(kv3.y) * FILTERS + f];
            float xv0 = bf2f(xin[(size_t)(i0 + ii    ) * FILTERS + f]);
            float xv1 = bf2f(xin[(size_t)(i0 + ii + 1) * FILTERS + f]);
            float xv2 = bf2f(xin[(size_t)(i0 + ii + 2) * FILTERS + f]);
            float xv3 = bf2f(xin[(size_t)(i0 + ii + 3) * FILTERS + f]);
            float lo0 = __uint_as_float(p0 << 16), hi0 = __uint_as_float(p0 & 0xffff0000u);
            float lo1 = __uint_as_float(p1 << 16), hi1 = __uint_as_float(p1 & 0xffff0000u);
            float lo2 = __uint_as_float(p2 << 16), hi2 = __uint_as_float(p2 & 0xffff0000u);
            float lo3 = __uint_as_float(p3 << 16), hi3 = __uint_as_float(p3 & 0xffff0000u);
            acc0 = fmaf(xv0, fmaf(kv0.x, hi0 - lo0, lo0), acc0);
            acc1 = fmaf(xv1, fmaf(kv1.x, hi1 - lo1, lo1), acc1);
            acc2 = fmaf(xv2, fmaf(kv2.x, hi2 - lo2, lo2), acc2);
            acc3 = fmaf(xv3, fmaf(kv3.x, hi3 - lo3, lo3), acc3);
        }
        s_red[half][f] = (acc0 + acc1) + (acc2 + acc3);
        __syncthreads();
        if (half == 0) s_agg[f] = s_red[0][f] + s_red[1][f];
        __syncthreads();
        // ---- x update: 128-dot split over halves (64 each) ----
        float v = 0.f;
        #pragma unroll 8
        for (int ff = half * 64; ff < half * 64 + 64; ff++)
            v = fmaf(s_agg[ff], w2[(size_t)ff * HIDDEN + f], v);
        s_red[half][f] = v;
        __syncthreads();
        if (half == 0) {
            float xnew = x[(size_t)j * HIDDEN + f] + b2[f] + s_red[0][f] + s_red[1][f];
            x[(size_t)j * HIDDEN + f] = xnew;
            s_xn[f] = xnew;
        }
        __syncthreads();
        if (l < N_LAYERS - 1) {
            float a2 = 0.f;
            #pragma unroll 8
            for (int hh = half * 64; hh < half * 64 + 64; hh++)
                a2 = fmaf(s_xn[hh], w1n[(size_t)hh * FILTERS + f], a2);
            s_red[half][f] = a2;
            __syncthreads();
            if (half == 0)
                xout[(size_t)j * FILTERS + f] = f2bf(b1n[f] + s_red[0][f] + s_red[1][f]);
        }
        grid.sync();
    }

    // ---------------- POOL: blocks 0..15 (one molecule each) ----------------
    if (bid < N_MOL) {
        int m = bid;
        if (t == 0) { s_lo = 0; s_cnt = 0; }
        __syncthreads();
        {   // parallel segment bounds on sorted batch
            int b0 = batch[t], b1 = batch[t + 256];
            atomicAdd(&s_lo,  (b0 <  m) + (b1 <  m));
            atomicAdd(&s_cnt, (b0 == m) + (b1 == m));
        }
        __syncthreads();
        int lo = s_lo, cnt = s_cnt, hi = lo + cnt;
        float s = 0.f;
        for (int i = lo + half; i < hi; i += 2) s += x[(size_t)i * HIDDEN + f];
        s_red[half][f] = s;
        __syncthreads();
        if (half == 0) s_mol[f] = (s_red[0][f] + s_red[1][f]) / (float)(cnt > 0 ? cnt : 1);
        __syncthreads();
        int o = t & 63, sl = t >> 6;
        float a = 0.f;
        #pragma unroll 8
        for (int h = sl * 32; h < sl * 32 + 32; h++) a = fmaf(s_mol[h], ow1[h * 64 + o], a);
        float* sr = (float*)s_red;               // reuse as [4][64]
        __syncthreads();
        sr[sl * 64 + o] = a;
        __syncthreads();
        if (t < 64) {
            float v = ob1[t] + sr[t] + sr[64 + t] + sr[128 + t] + sr[192 + t];
            s_hh[t] = v / (1.f + __expf(-v));    // silu
        }
        __syncthreads();
        if (t < 64) {
            float v = s_hh[t] * ow2[t];
            for (int off = 32; off > 0; off >>= 1) v += __shfl_down(v, off, 64);
            if (t == 0) out[m] = v + ob2[0];
        }
    }
}

extern "C" void kernel_launch(void* const* d_in, const int* in_sizes, int n_in,
                              void* d_out, int out_size, void* d_ws, size_t ws_size,
                              hipStream_t stream) {
    const int*   an    = (const int*)  d_in[0];
    const float* pos   = (const float*)d_in[1];
    const int*   batch = (const int*)  d_in[2];
    const float* emb   = (const float*)d_in[3];
    const float* fw1   = (const float*)d_in[4];
    const float* fb1   = (const float*)d_in[5];
    const float* fw2   = (const float*)d_in[6];
    const float* fb2   = (const float*)d_in[7];
    const float* d1w   = (const float*)d_in[8];
    const float* d1b   = (const float*)d_in[9];
    const float* d2w   = (const float*)d_in[10];
    const float* d2b   = (const float*)d_in[11];
    const float* ow1   = (const float*)d_in[12];
    const float* ob1   = (const float*)d_in[13];
    const float* ow2   = (const float*)d_in[14];
    const float* ob2   = (const float*)d_in[15];
    float* out = (float*)d_out;

    float*          x    = (float*)d_ws;                               // 256 KB
    unsigned short* xjA  = (unsigned short*)(x + N_ATOMS * HIDDEN);    // 128 KB
    unsigned short* xjB  = xjA + (size_t)N_ATOMS * FILTERS;            // 128 KB
    unsigned short* tab  = xjB + (size_t)N_ATOMS * FILTERS;            // 1.575 MB

    void* args[] = { (void*)&an, (void*)&pos, (void*)&batch, (void*)&emb,
                     (void*)&fw1, (void*)&fb1, (void*)&fw2, (void*)&fb2,
                     (void*)&d1w, (void*)&d1b, (void*)&d2w, (void*)&d2b,
                     (void*)&ow1, (void*)&ob1, (void*)&ow2, (void*)&ob2,
                     (void*)&x, (void*)&xjA, (void*)&xjB, (void*)&tab,
                     (void*)&out };
    hipLaunchCooperativeKernel((const void*)k_all, dim3(GRID), dim3(BLK),
                               args, 0, stream);
}

// Round 8
// 74.645 us; speedup vs baseline: 4.2686x; 4.2686x over previous
//
#include <hip/hip_runtime.h>
#include <math.h>

#define N_ATOMS 512
#define N_MOL   16
#define HIDDEN  128
#define FILTERS 128
#define NUM_RBF 50
#define CUTOFF  10.0f
#define N_LAYERS 3

#define KBINS  1024              // lerp bins over [0, CUTOFF]
#define NBINS  (KBINS + 2)       // bins evaluated 0..1025 (>=1024 give env=0)
#define PROWS  (KBINS + 1)       // pair rows 0..1024; row k = {phi_k, phi_{k+1}} bf16
#define TOTW   (N_LAYERS * NBINS)        // 3078 table wave-units
#define TWBLK  ((TOTW + 7) / 8)          // 385 table blocks (8 waves each)
#define EMBB   8                         // emb blocks, 64 atoms each
#define PI_F   3.14159265358979f

__device__ __forceinline__ unsigned short f2bf(float v) {
    unsigned u = __float_as_uint(v);
    u += 0x7fffu + ((u >> 16) & 1u);     // round-to-nearest-even
    return (unsigned short)(u >> 16);
}
__device__ __forceinline__ float bf2f(unsigned short u) {
    return __uint_as_float((unsigned)u << 16);
}

// ============ front kernel: filter tables (1 bin per wave) ∥ embedding+xj0 ============
// (unchanged from R6 — proven cheap by the R6 differential experiment)
__global__ void __launch_bounds__(512) k_front(
        const int* __restrict__ an, const float* __restrict__ emb,
        const float* __restrict__ d1w, const float* __restrict__ d1b,
        const float* __restrict__ fw1, const float* __restrict__ fb1,
        const float* __restrict__ fw2, const float* __restrict__ fb2,
        float* __restrict__ x, unsigned short* __restrict__ xj,
        unsigned short* __restrict__ tab) {
    __shared__ float s_sh[8][HIDDEN];
    __shared__ __align__(16) float s_row[64][HIDDEN];
    __shared__ int   s_an[64];
    int bid = blockIdx.x, t = threadIdx.x;

    if (bid < TWBLK) {
        int wv = t >> 6, lane = t & 63;
        int w  = bid * 8 + wv;
        int wc = w < TOTW ? w : TOTW - 1;        // clamp idle waves
        int l  = wc / NBINS;
        int bin = wc - l * NBINS;
        float dd = bin * (CUTOFF / (float)KBINS);
        const float* w1g = fw1 + (size_t)l * NUM_RBF * FILTERS;
        const float* w2g = fw2 + (size_t)l * FILTERS * FILTERS;
        int c0 = lane, c1 = lane + 64;
        float h0 = fb1[l * FILTERS + c0];
        float h1 = fb1[l * FILTERS + c1];
        #pragma unroll 5
        for (int r = 0; r < NUM_RBF; r++) {
            float cr = r * (CUTOFF / (float)(NUM_RBF - 1));
            float xx = dd - cr;
            float rb = __expf(-xx * xx * 12.5f);          // 1/(2*w^2), w = 0.2
            h0 = fmaf(rb, w1g[r * FILTERS + c0], h0);
            h1 = fmaf(rb, w1g[r * FILTERS + c1], h1);
        }
        s_sh[wv][c0] = h0 / (1.f + __expf(-h0));          // silu
        s_sh[wv][c1] = h1 / (1.f + __expf(-h1));
        __syncthreads();
        float o0 = fb2[l * FILTERS + c0];
        float o1 = fb2[l * FILTERS + c1];
        #pragma unroll 4
        for (int hh = 0; hh < FILTERS; hh++) {
            float hv = s_sh[wv][hh];
            o0 = fmaf(hv, w2g[hh * FILTERS + c0], o0);
            o1 = fmaf(hv, w2g[hh * FILTERS + c1], o1);
        }
        float env = (bin >= KBINS) ? 0.f
                  : 0.5f * (__cosf(dd * (PI_F / CUTOFF)) + 1.f);
        unsigned short p0 = f2bf(o0 * env), p1 = f2bf(o1 * env);
        size_t base = (size_t)l * PROWS * FILTERS * 2;
        if (w < TOTW) {
            if (bin <= KBINS) {
                tab[base + ((size_t)bin * FILTERS + c0) * 2 + 0] = p0;
                tab[base + ((size_t)bin * FILTERS + c1) * 2 + 0] = p1;
            }
            if (bin >= 1) {
                tab[base + ((size_t)(bin - 1) * FILTERS + c0) * 2 + 1] = p0;
                tab[base + ((size_t)(bin - 1) * FILTERS + c1) * 2 + 1] = p1;
            }
        }
    } else {
        int eb = bid - TWBLK;
        int i0 = eb * 64;
        if (t < 64) s_an[t] = an[i0 + t];
        __syncthreads();
        for (int idx = t; idx < 64 * HIDDEN; idx += 512) {
            int a = idx >> 7, c = idx & 127;
            float v = emb[(size_t)s_an[a] * HIDDEN + c];
            s_row[a][c] = v;
            x[(size_t)(i0 + a) * HIDDEN + c] = v;
        }
        __syncthreads();
        int cq = t & 31, ag = t >> 5;
        float o[4][4];
        float4 bv = *(const float4*)(d1b + 4 * cq);
        float bva[4] = { bv.x, bv.y, bv.z, bv.w };
        #pragma unroll
        for (int aa = 0; aa < 4; aa++)
            #pragma unroll
            for (int cc = 0; cc < 4; cc++) o[aa][cc] = bva[cc];
        #pragma unroll 4
        for (int h = 0; h < HIDDEN; h += 2) {
            float4 wA = *(const float4*)(d1w + (size_t)h * FILTERS + 4 * cq);
            float4 wB = *(const float4*)(d1w + (size_t)(h + 1) * FILTERS + 4 * cq);
            float wa[4] = { wA.x, wA.y, wA.z, wA.w };
            float wb[4] = { wB.x, wB.y, wB.z, wB.w };
            #pragma unroll
            for (int aa = 0; aa < 4; aa++) {
                float2 hp = *(const float2*)(&s_row[ag * 4 + aa][h]);
                #pragma unroll
                for (int cc = 0; cc < 4; cc++) {
                    o[aa][cc] = fmaf(hp.x, wa[cc], o[aa][cc]);
                    o[aa][cc] = fmaf(hp.y, wb[cc], o[aa][cc]);
                }
            }
        }
        #pragma unroll
        for (int aa = 0; aa < 4; aa++) {
            int i = i0 + ag * 4 + aa;
            #pragma unroll
            for (int cp = 0; cp < 2; cp++) {
                unsigned int pk = (unsigned)f2bf(o[aa][2 * cp]) |
                                  ((unsigned)f2bf(o[aa][2 * cp + 1]) << 16);
                *(unsigned int*)(xj + (size_t)i * FILTERS + 4 * cq + 2 * cp) = pk;
            }
        }
    }
}

// ======== layer kernel: f-paired gather (uint2 tab row + uint xj), one j per block ========
// 512 threads = 8 waves; wave wv sums i in [wv*64, wv*64+64); lane e owns channels {2e,2e+1}.
// Distances recomputed from LDS pos each layer (no kw buffer at all).
template<int LAST>
__global__ void __launch_bounds__(512) k_layer(const float* __restrict__ pos,
        const unsigned int* __restrict__ tabl, const unsigned short* __restrict__ xj_in,
        float* __restrict__ x, const float* __restrict__ w2, const float* __restrict__ b2,
        const float* __restrict__ w1n, const float* __restrict__ b1n,
        unsigned short* __restrict__ xj_out) {
    int j = blockIdx.x;
    int t = threadIdx.x;
    int wv = t >> 6, e = t & 63;
    __shared__ float  s_pos[N_ATOMS * 3];
    __shared__ float2 s_kw[N_ATOMS];
    __shared__ float  s_part[8][FILTERS];
    __shared__ float  s_red[4][FILTERS];
    __shared__ float  s_agg[FILTERS];
    __shared__ float  s_xn[HIDDEN];
    for (int idx = t; idx < N_ATOMS * 3; idx += 512) s_pos[idx] = pos[idx];
    __syncthreads();
    {   // one distance per thread
        float pjx = s_pos[j*3+0], pjy = s_pos[j*3+1], pjz = s_pos[j*3+2];
        float dx = s_pos[t*3+0] - pjx;
        float dy = s_pos[t*3+1] - pjy;
        float dz = s_pos[t*3+2] - pjz;
        float d  = sqrtf(dx*dx + dy*dy + dz*dz);
        int k; float w;
        if (t == j || d >= CUTOFF) { k = KBINS; w = 0.f; }
        else {
            float tt = d * ((float)KBINS / CUTOFF);
            k = (int)tt;
            if (k > KBINS - 1) k = KBINS - 1;
            w = tt - (float)k;
        }
        s_kw[t] = make_float2(w, __int_as_float(k));
    }
    __syncthreads();
    // ---- aggregation: 64 i per wave, 2 channels per lane, 2-way i-unroll ----
    const uint2*        tab2 = (const uint2*)tabl;
    const unsigned int* xju  = (const unsigned int*)xj_in;
    float ae0 = 0.f, ao0 = 0.f, ae1 = 0.f, ao1 = 0.f;
    int i0 = wv * 64;
    #pragma unroll 4
    for (int ii = 0; ii < 64; ii += 2) {
        float2 kv0 = s_kw[i0 + ii];
        float2 kv1 = s_kw[i0 + ii + 1];
        uint2 p0 = tab2[(size_t)__float_as_int(kv0.y) * 64 + e];   // 8B: channels 2e,2e+1
        uint2 p1 = tab2[(size_t)__float_as_int(kv1.y) * 64 + e];
        unsigned int xu0 = xju[(size_t)(i0 + ii    ) * 64 + e];    // 4B: 2 bf16
        unsigned int xu1 = xju[(size_t)(i0 + ii + 1) * 64 + e];
        float xe0 = __uint_as_float(xu0 << 16), xo0 = __uint_as_float(xu0 & 0xffff0000u);
        float xe1 = __uint_as_float(xu1 << 16), xo1 = __uint_as_float(xu1 & 0xffff0000u);
        float le0 = __uint_as_float(p0.x << 16), he0 = __uint_as_float(p0.x & 0xffff0000u);
        float lo0 = __uint_as_float(p0.y << 16), ho0 = __uint_as_float(p0.y & 0xffff0000u);
        float le1 = __uint_as_float(p1.x << 16), he1 = __uint_as_float(p1.x & 0xffff0000u);
        float lo1 = __uint_as_float(p1.y << 16), ho1 = __uint_as_float(p1.y & 0xffff0000u);
        ae0 = fmaf(xe0, fmaf(kv0.x, he0 - le0, le0), ae0);
        ao0 = fmaf(xo0, fmaf(kv0.x, ho0 - lo0, lo0), ao0);
        ae1 = fmaf(xe1, fmaf(kv1.x, he1 - le1, le1), ae1);
        ao1 = fmaf(xo1, fmaf(kv1.x, ho1 - lo1, lo1), ao1);
    }
    s_part[wv][2 * e]     = ae0 + ae1;
    s_part[wv][2 * e + 1] = ao0 + ao1;
    __syncthreads();
    if (t < FILTERS) {
        float s = 0.f;
        #pragma unroll
        for (int w8 = 0; w8 < 8; w8++) s += s_part[w8][t];
        s_agg[t] = s;
    }
    __syncthreads();
    // ---- x update: c = t&127, 4 segments of 32 ----
    int c = t & 127, seg = t >> 7;
    float v = 0.f;
    #pragma unroll 8
    for (int ff = seg * 32; ff < seg * 32 + 32; ff++)
        v = fmaf(s_agg[ff], w2[(size_t)ff * HIDDEN + c], v);
    s_red[seg][c] = v;
    __syncthreads();
    if (seg == 0) {
        float xnew = x[(size_t)j * HIDDEN + c] + b2[c]
                   + s_red[0][c] + s_red[1][c] + s_red[2][c] + s_red[3][c];
        x[(size_t)j * HIDDEN + c] = xnew;
        s_xn[c] = xnew;
    }
    __syncthreads();
    if (!LAST) {
        float a2 = 0.f;
        #pragma unroll 8
        for (int hh = seg * 32; hh < seg * 32 + 32; hh++)
            a2 = fmaf(s_xn[hh], w1n[(size_t)hh * FILTERS + c], a2);
        s_red[seg][c] = a2;
        __syncthreads();
        if (seg == 0)
            xj_out[(size_t)j * FILTERS + c] =
                f2bf(b1n[c] + s_red[0][c] + s_red[1][c] + s_red[2][c] + s_red[3][c]);
    }
}

// ============ molecule pool + output MLP (unchanged from R6) ============
__global__ void __launch_bounds__(256) k_pool(const float* __restrict__ x,
        const int* __restrict__ batch, const float* __restrict__ ow1,
        const float* __restrict__ ob1, const float* __restrict__ ow2,
        const float* __restrict__ ob2, float* __restrict__ out) {
    int m = blockIdx.x, t = threadIdx.x;
    __shared__ float s_red[2][FILTERS];
    __shared__ float s_mol[HIDDEN];
    __shared__ float s_hh[64];
    __shared__ int   s_lo, s_cnt;
    if (t == 0) { s_lo = 0; s_cnt = 0; }
    __syncthreads();
    {
        int b0 = batch[t], b1 = batch[t + 256];
        atomicAdd(&s_lo,  (b0 <  m) + (b1 <  m));
        atomicAdd(&s_cnt, (b0 == m) + (b1 == m));
    }
    __syncthreads();
    int lo = s_lo, cnt = s_cnt, hi = lo + cnt;
    int f = t & 127, half = t >> 7;
    float s = 0.f;
    for (int i = lo + half; i < hi; i += 2) s += x[(size_t)i * HIDDEN + f];
    s_red[half][f] = s;
    __syncthreads();
    if (half == 0) s_mol[f] = (s_red[0][f] + s_red[1][f]) / (float)(cnt > 0 ? cnt : 1);
    __syncthreads();
    int o = t & 63, sl = t >> 6;
    float a = 0.f;
    #pragma unroll 8
    for (int h = sl * 32; h < sl * 32 + 32; h++) a = fmaf(s_mol[h], ow1[h * 64 + o], a);
    float* sr = (float*)s_red;
    __syncthreads();
    sr[sl * 64 + o] = a;
    __syncthreads();
    if (t < 64) {
        float v = ob1[t] + sr[t] + sr[64 + t] + sr[128 + t] + sr[192 + t];
        s_hh[t] = v / (1.f + __expf(-v));
    }
    __syncthreads();
    if (t < 64) {
        float v = s_hh[t] * ow2[t];
        for (int off = 32; off > 0; off >>= 1) v += __shfl_down(v, off, 64);
        if (t == 0) out[m] = v + ob2[0];
    }
}

extern "C" void kernel_launch(void* const* d_in, const int* in_sizes, int n_in,
                              void* d_out, int out_size, void* d_ws, size_t ws_size,
                              hipStream_t stream) {
    const int*   an    = (const int*)  d_in[0];
    const float* pos   = (const float*)d_in[1];
    const int*   batch = (const int*)  d_in[2];
    const float* emb   = (const float*)d_in[3];
    const float* fw1   = (const float*)d_in[4];
    const float* fb1   = (const float*)d_in[5];
    const float* fw2   = (const float*)d_in[6];
    const float* fb2   = (const float*)d_in[7];
    const float* d1w   = (const float*)d_in[8];
    const float* d1b   = (const float*)d_in[9];
    const float* d2w   = (const float*)d_in[10];
    const float* d2b   = (const float*)d_in[11];
    const float* ow1   = (const float*)d_in[12];
    const float* ob1   = (const float*)d_in[13];
    const float* ow2   = (const float*)d_in[14];
    const float* ob2   = (const float*)d_in[15];
    float* out = (float*)d_out;

    float*          x    = (float*)d_ws;                               // 256 KB
    unsigned short* xjA  = (unsigned short*)(x + N_ATOMS * HIDDEN);    // 128 KB
    unsigned short* xjB  = xjA + (size_t)N_ATOMS * FILTERS;            // 128 KB
    unsigned short* tab  = xjB + (size_t)N_ATOMS * FILTERS;            // 1.575 MB

    k_front<<<TWBLK + EMBB, 512, 0, stream>>>(
        an, emb, d1w, d1b, fw1, fb1, fw2, fb2, x, xjA, tab);

    const unsigned int* t0 = (const unsigned int*)(tab + (size_t)0 * PROWS * FILTERS * 2);
    const unsigned int* t1 = (const unsigned int*)(tab + (size_t)1 * PROWS * FILTERS * 2);
    const unsigned int* t2 = (const unsigned int*)(tab + (size_t)2 * PROWS * FILTERS * 2);

    k_layer<0><<<N_ATOMS, 512, 0, stream>>>(pos, t0, xjA, x,
        d2w + (size_t)0*FILTERS*HIDDEN, d2b + (size_t)0*HIDDEN,
        d1w + (size_t)1*HIDDEN*FILTERS, d1b + (size_t)1*FILTERS, xjB);
    k_layer<0><<<N_ATOMS, 512, 0, stream>>>(pos, t1, xjB, x,
        d2w + (size_t)1*FILTERS*HIDDEN, d2b + (size_t)1*HIDDEN,
        d1w + (size_t)2*HIDDEN*FILTERS, d1b + (size_t)2*FILTERS, xjA);
    k_layer<1><<<N_ATOMS, 512, 0, stream>>>(pos, t2, xjA, x,
        d2w + (size_t)2*FILTERS*HIDDEN, d2b + (size_t)2*HIDDEN,
        d1w, d1b, xjB);

    k_pool<<<N_MOL, 256, 0, stream>>>(x, batch, ow1, ob1, ow2, ob2, out);
}